// Round 10
// baseline (268.979 us; speedup 1.0000x reference)
//
#include <hip/hip_runtime.h>
#include <hip/hip_bf16.h>
#include <math.h>

#define BB 2
#define DD 8
#define NN 40
#define HH 128
#define HID 512
#define NJK 1600            // NN*NN
#define MROW 64000          // NN*NJK rows per batch

typedef __attribute__((ext_vector_type(8))) short short8;
typedef __attribute__((ext_vector_type(4))) float floatx4;

static __device__ __forceinline__ unsigned short f2bf(float x) {
    unsigned int b = __float_as_uint(x);
    b += 0x7fffu + ((b >> 16) & 1u);
    return (unsigned short)(b >> 16);
}

static __device__ __forceinline__ short bfr(float x) {   // relu + bf16(RNE)
    x = fmaxf(x, 0.f);
    __hip_bfloat16 h = __float2bfloat16(x);
    return (short)__builtin_bit_cast(unsigned short, h);
}

#define COORD(tau, b_, i0_, jk0_) do { \
    int _b = (tau)/1000; int _rem = (tau) - _b*1000; \
    int _ig = _rem/100;  int _jc = _rem - _ig*100; \
    b_ = _b; i0_ = _ig*4; jk0_ = _jc*16; } while (0)

// Fused prep, 426 blocks x 256 (known-good since R5):
//  bid [0,400)   : hp rows bid*8..+7      (max_d(pair) @ W1p, fp32)
//  bid [400,410) : hnb rows (bid-400)*8..+7  (max_d(node) @ W1n + b1)
//  bid [410,426) : w2f — W2 k-slice ks=bid-410 packed bf16 in MFMA-frag order
__global__ __launch_bounds__(256) void prep_kernel(
        const float* __restrict__ node, const float* __restrict__ pair,
        const float* __restrict__ W1n, const float* __restrict__ W1p,
        const float* __restrict__ b1, const float* __restrict__ W2,
        float* __restrict__ hp, float* __restrict__ hnb,
        unsigned short* __restrict__ w2f) {
    __shared__ float smem[32 * 513];
    const int bid = blockIdx.x;
    const int t = threadIdx.x;

    if (bid < 400) {                                   // ---- hp ----
        float (*pf)[HH] = (float (*)[HH])smem;
        const int rowbase = bid * 8;
        #pragma unroll
        for (int e = t; e < 8*HH; e += 256) {
            int r8 = e >> 7, c = e & 127;
            int grow = rowbase + r8;
            int b = grow / NJK, jk = grow - b*NJK;
            float m = -INFINITY;
            #pragma unroll
            for (int d = 0; d < DD; ++d)
                m = fmaxf(m, pair[((size_t)((b*DD + d)*NJK + jk))*HH + c]);
            pf[r8][c] = m;
        }
        __syncthreads();
        const int rg = t >> 7, c4 = (t & 127) * 4;
        float4 acc[4];
        #pragma unroll
        for (int r = 0; r < 4; ++r) acc[r] = make_float4(0.f,0.f,0.f,0.f);
        #pragma unroll 4
        for (int h = 0; h < HH; ++h) {
            float4 wv = *(const float4*)&W1p[h*HID + c4];
            #pragma unroll
            for (int r = 0; r < 4; ++r) {
                float pv = pf[rg*4 + r][h];
                acc[r].x = fmaf(pv, wv.x, acc[r].x);
                acc[r].y = fmaf(pv, wv.y, acc[r].y);
                acc[r].z = fmaf(pv, wv.z, acc[r].z);
                acc[r].w = fmaf(pv, wv.w, acc[r].w);
            }
        }
        #pragma unroll
        for (int r = 0; r < 4; ++r)
            *(float4*)&hp[(size_t)(rowbase + rg*4 + r)*HID + c4] = acc[r];
    } else if (bid < 410) {                            // ---- hnb ----
        float (*nf)[HH] = (float (*)[HH])smem;
        const int rowbase = (bid - 400) * 8;
        #pragma unroll
        for (int e = t; e < 8*HH; e += 256) {
            int r8 = e >> 7, c = e & 127;
            int grow = rowbase + r8;
            int b = grow / NN, i = grow - b*NN;
            float m = -INFINITY;
            #pragma unroll
            for (int d = 0; d < DD; ++d)
                m = fmaxf(m, node[((size_t)((b*DD + d)*NN + i))*HH + c]);
            nf[r8][c] = m;
        }
        __syncthreads();
        const int rg = t >> 7, c4 = (t & 127) * 4;
        float4 acc[4];
        #pragma unroll
        for (int r = 0; r < 4; ++r) acc[r] = make_float4(0.f,0.f,0.f,0.f);
        #pragma unroll 4
        for (int h = 0; h < HH; ++h) {
            float4 wv = *(const float4*)&W1n[h*HID + c4];
            #pragma unroll
            for (int r = 0; r < 4; ++r) {
                float nv = nf[rg*4 + r][h];
                acc[r].x = fmaf(nv, wv.x, acc[r].x);
                acc[r].y = fmaf(nv, wv.y, acc[r].y);
                acc[r].z = fmaf(nv, wv.z, acc[r].z);
                acc[r].w = fmaf(nv, wv.w, acc[r].w);
            }
        }
        float4 b1v = *(const float4*)&b1[c4];
        #pragma unroll
        for (int r = 0; r < 4; ++r) {
            float4 o = make_float4(acc[r].x + b1v.x, acc[r].y + b1v.y,
                                   acc[r].z + b1v.z, acc[r].w + b1v.w);
            *(float4*)&hnb[(size_t)(rowbase + rg*4 + r)*HID + c4] = o;
        }
    } else {                                           // ---- w2f ----
        const int ks = bid - 410;
        for (int e = t; e < 32*HID; e += 256) {
            int r = e >> 9, c = e & 511;
            smem[r*513 + c] = W2[(size_t)(ks*32 + r)*HID + c];
        }
        __syncthreads();
        const int w = t >> 6, l = t & 63;
        const int lr = l & 15, lg = l >> 4;
        #pragma unroll
        for (int f = 0; f < 8; ++f) {
            int cf = w*8 + f;
            short8 u;
            #pragma unroll
            for (int kk = 0; kk < 8; ++kk)
                u[kk] = (short)f2bf(smem[(lg*8 + kk)*513 + cf*16 + lr]);
            *(short8*)(w2f + (size_t)(cf*16 + ks)*512 + l*8) = u;
        }
    }
}

// Main: 250 persistent blocks x 512 (8 waves), 1 block/CU, 8 tiles each.
// Tile = 4 i x 16 jk = 64 rows x 512 cols, MFMA-frag-packed h1 in LDS,
// DOUBLE-BUFFERED (2 x 64KB): stage of tile tt+1 interleaved into k-loop of
// tile tt (issue loads at even ks, cvt+ds_write at odd ks). A-frags 1-step
// ds_read prefetch; B-frags 1-step global prefetch from w2f (L2).
// Wave w = all 64 rows x cols [w*64,(w+1)*64): acc[4][4]. 2 barriers/tile.
__global__ __launch_bounds__(512, 2) void main_kernel(
        const float* __restrict__ hp, const float* __restrict__ hnb,
        const unsigned short* __restrict__ w2f,
        const float* __restrict__ b2, const float* __restrict__ W3,
        const float* __restrict__ b3, const float* __restrict__ scale,
        const float* __restrict__ bias, float* __restrict__ out) {
    __shared__ __align__(16) unsigned short h1d[2 * 32768];  // 2 x 64 KiB
    __shared__ float red[8][64];

    const int bid = blockIdx.x;                        // 0..249
    const int xq = bid & 7, xi = bid >> 3;             // bijective XCD swizzle
    const int sb = (xq < 2) ? xq*32 + xi : 64 + (xq - 2)*31 + xi;
    const int t = threadIdx.x;
    const int ww = t >> 6, l = t & 63;
    const int lr = l & 15, lg = l >> 4;
    char* h1c = (char*)h1d;

    const unsigned short* bbase = w2f + (size_t)ww*32768 + l*8;

    // epilogue constants (cols fixed per wave across tiles)
    float b2v[4], w3v[4];
    #pragma unroll
    for (int tn = 0; tn < 4; ++tn) {
        int col = ww*64 + tn*16 + lr;
        b2v[tn] = b2[col];
        w3v[tn] = W3[col];
    }

    // ---- prologue: stage tile sb*8 into buf0 (wave ww: frags ks=ww*2..+1) ----
    {
        int b0, i00, jk00;
        COORD(sb*8, b0, i00, jk00);
        #pragma unroll
        for (int j = 0; j < 8; ++j) {
            const int ksf = ww*2 + (j >> 2), smi = j & 3;
            const float* hr = hp  + ((size_t)(b0*NJK + jk00 + lr))*HID + ksf*32 + lg*8;
            const float* nr = hnb + ((size_t)(b0*NN  + i00 + smi))*HID + ksf*32 + lg*8;
            float4 p0 = *(const float4*)hr, p1 = *(const float4*)(hr + 4);
            float4 n0 = *(const float4*)nr, n1 = *(const float4*)(nr + 4);
            short8 u;
            u[0] = bfr(p0.x + n0.x); u[1] = bfr(p0.y + n0.y);
            u[2] = bfr(p0.z + n0.z); u[3] = bfr(p0.w + n0.w);
            u[4] = bfr(p1.x + n1.x); u[5] = bfr(p1.y + n1.y);
            u[6] = bfr(p1.z + n1.z); u[7] = bfr(p1.w + n1.w);
            *(short8*)(h1c + ((ksf*4 + smi) << 10) + l*16) = u;
        }
    }
    __syncthreads();

    short8 bcur[4];
    #pragma unroll
    for (int tn = 0; tn < 4; ++tn)
        bcur[tn] = *(const short8*)(bbase + ((tn*16) << 9));

    for (int tt = 0; tt < 8; ++tt) {
        const int tau = sb*8 + tt;
        int b, i0, jk0;   COORD(tau, b, i0, jk0);
        int bn, i0n, jk0n; COORD(tau + 1, bn, i0n, jk0n);   // used iff tt<7
        const int cur = tt & 1;
        char* bufc = h1c + cur*65536;
        char* bufn = h1c + (cur ^ 1)*65536;
        const bool st = (tt < 7);

        floatx4 acc[4][4];
        #pragma unroll
        for (int mi = 0; mi < 4; ++mi)
            #pragma unroll
            for (int tn = 0; tn < 4; ++tn)
                acc[mi][tn] = (floatx4){0.f, 0.f, 0.f, 0.f};

        short8 acur[4], anxt[4];
        #pragma unroll
        for (int mi = 0; mi < 4; ++mi)
            acur[mi] = *(const short8*)(bufc + (mi << 10) + l*16);

        float4 sp0, sp1, sn0, sn1;                     // stage in-flight regs

        #pragma unroll
        for (int ks = 0; ks < 16; ++ks) {
            // B prefetch (wraps to ks=0 at the end -> carries into next tile)
            short8 bnxt[4];
            const int ksn = (ks + 1) & 15;
            #pragma unroll
            for (int tn = 0; tn < 4; ++tn)
                bnxt[tn] = *(const short8*)(bbase + ((tn*16 + ksn) << 9));
            // A prefetch
            if (ks < 15) {
                #pragma unroll
                for (int mi = 0; mi < 4; ++mi)
                    anxt[mi] = *(const short8*)(bufc + (((ks+1)*4 + mi) << 10) + l*16);
            }
            // interleaved stage of tile tt+1: issue at even ks, write at odd ks
            if ((ks & 1) == 0) {
                if (st) {
                    const int j = ks >> 1;
                    const int ksf = ww*2 + (j >> 2), smi = j & 3;
                    const float* hr = hp  + ((size_t)(bn*NJK + jk0n + lr))*HID + ksf*32 + lg*8;
                    const float* nr = hnb + ((size_t)(bn*NN  + i0n + smi))*HID + ksf*32 + lg*8;
                    sp0 = *(const float4*)hr; sp1 = *(const float4*)(hr + 4);
                    sn0 = *(const float4*)nr; sn1 = *(const float4*)(nr + 4);
                }
            } else {
                if (st) {
                    const int j = ks >> 1;
                    const int ksf = ww*2 + (j >> 2), smi = j & 3;
                    short8 u;
                    u[0] = bfr(sp0.x + sn0.x); u[1] = bfr(sp0.y + sn0.y);
                    u[2] = bfr(sp0.z + sn0.z); u[3] = bfr(sp0.w + sn0.w);
                    u[4] = bfr(sp1.x + sn1.x); u[5] = bfr(sp1.y + sn1.y);
                    u[6] = bfr(sp1.z + sn1.z); u[7] = bfr(sp1.w + sn1.w);
                    *(short8*)(bufn + ((ksf*4 + smi) << 10) + l*16) = u;
                }
            }
            // MFMA cluster
            __builtin_amdgcn_s_setprio(1);
            #pragma unroll
            for (int mi = 0; mi < 4; ++mi)
                #pragma unroll
                for (int tn = 0; tn < 4; ++tn)
                    acc[mi][tn] = __builtin_amdgcn_mfma_f32_16x16x32_bf16(acur[mi], bcur[tn], acc[mi][tn], 0, 0, 0);
            __builtin_amdgcn_s_setprio(0);
            #pragma unroll
            for (int tn = 0; tn < 4; ++tn) bcur[tn] = bnxt[tn];
            if (ks < 15) {
                #pragma unroll
                for (int mi = 0; mi < 4; ++mi) acur[mi] = anxt[mi];
            }
        }
        __syncthreads();   // cur-buf reads done + next-buf writes done

        // ---- epilogue: v = relu(acc+b2)@W3, reduce over col-waves, sigmoid ----
        #pragma unroll
        for (int mi = 0; mi < 4; ++mi) {
            #pragma unroll
            for (int q = 0; q < 4; ++q) {
                float s = 0.f;
                #pragma unroll
                for (int tn = 0; tn < 4; ++tn)
                    s += fmaxf(acc[mi][tn][q] + b2v[tn], 0.f) * w3v[tn];
                s += __shfl_xor(s, 1);
                s += __shfl_xor(s, 2);
                s += __shfl_xor(s, 4);
                s += __shfl_xor(s, 8);
                if (lr == 0) red[ww][mi*16 + lg*4 + q] = s;
            }
        }
        __syncthreads();
        if (t < 64) {
            float v = b3[0];
            #pragma unroll
            for (int c = 0; c < 8; ++c) v += red[c][t];
            float z = scale[0]*v + bias[0];
            out[(size_t)b*MROW + (size_t)(i0 + (t >> 4))*NJK + jk0 + (t & 15)] =
                1.0f / (1.0f + expf(-z));
        }
        // out-write overlaps next tile's k-loop start; no extra barrier needed
    }
}

extern "C" void kernel_launch(void* const* d_in, const int* in_sizes, int n_in,
                              void* d_out, int out_size, void* d_ws, size_t ws_size,
                              hipStream_t stream) {
    const float* node  = (const float*)d_in[0];
    const float* pair  = (const float*)d_in[1];
    const float* W1n   = (const float*)d_in[2];
    const float* W1p   = (const float*)d_in[3];
    const float* b1    = (const float*)d_in[4];
    const float* W2    = (const float*)d_in[5];
    const float* b2    = (const float*)d_in[6];
    const float* W3    = (const float*)d_in[7];
    const float* b3    = (const float*)d_in[8];
    const float* scale = (const float*)d_in[9];
    const float* bias  = (const float*)d_in[10];
    float* out = (float*)d_out;

    float* hp  = (float*)d_ws;                                  // 3200*512 f32
    float* hnb = hp + (size_t)BB*NJK*HID;                       // 80*512 f32
    unsigned short* w2f = (unsigned short*)(hnb + BB*NN*HID);   // 512*512 bf16

    hipLaunchKernelGGL(prep_kernel, dim3(426), dim3(256), 0, stream,
                       node, pair, W1n, W1p, b1, W2, hp, hnb, w2f);
    hipLaunchKernelGGL(main_kernel, dim3(250), dim3(512), 0, stream,
                       hp, hnb, w2f, b2, W3, b3, scale, bias, out);
}